// Round 15
// baseline (1084.517 us; speedup 1.0000x reference)
//
#include <hip/hip_runtime.h>
#include <hip/hip_bf16.h>
#include <stdint.h>
#include <stddef.h>

static constexpr int BB = 16, NN = 256, TT = 4, HH = 128;
static constexpr int MM = BB * NN;     // 4096 rows
static constexpr int CC = 512;         // 4*H gate width
static constexpr int OUTV = 1000;
static constexpr int MAXS = 15;
static constexpr int SP = 132;         // f32 state row pitch in LDS
static constexpr int ND = 8;           // fused dispatches (2 steps each)

typedef float f32x4 __attribute__((ext_vector_type(4)));
typedef short s16x8 __attribute__((ext_vector_type(8)));
typedef unsigned long long u64;

__device__ __forceinline__ float sigf(float x) { return 1.0f / (1.0f + __expf(-x)); }
__device__ __forceinline__ float tanhr(float x) { return 2.0f / (1.0f + __expf(-2.0f * x)) - 1.0f; }
__device__ __forceinline__ unsigned short f2bu(float a) {
  return __builtin_bit_cast(unsigned short, __float2bfloat16(a));
}
__device__ __forceinline__ unsigned int packh(float a, float b) {
  return (unsigned int)f2bu(a) | ((unsigned int)f2bu(b) << 16);
}
__device__ __forceinline__ float blo(unsigned int u) { return __builtin_bit_cast(float, u << 16); }
__device__ __forceinline__ float bhi(unsigned int u) { return __builtin_bit_cast(float, u & 0xffff0000u); }

// LLC-coherent accesses (cross-XCD visible mid-kernel): relaxed agent-scope
// atomics -> global_load/store sc0 sc1, no cache maintenance. Correctness of
// this exact pattern (stores + __syncthreads drain + relaxed add publish,
// relaxed-load consume) was verified in round 4 (passed, exact absmax).
__device__ __forceinline__ u64 ld64_llc(const u64* p) {
  return __hip_atomic_load(p, __ATOMIC_RELAXED, __HIP_MEMORY_SCOPE_AGENT);
}
__device__ __forceinline__ void st64_llc(u64* p, u64 v) {
  __hip_atomic_store(p, v, __ATOMIC_RELAXED, __HIP_MEMORY_SCOPE_AGENT);
}
__device__ __forceinline__ float ldf_llc(const float* p) {
  return __hip_atomic_load(p, __ATOMIC_RELAXED, __HIP_MEMORY_SCOPE_AGENT);
}

// ---------------- setup kernels (2 dispatches, proven) ----------------

// per-batch CSR built entirely block-locally in LDS: 16 blocks x 512 threads
__global__ __launch_bounds__(512) void csr_kernel(const int* __restrict__ tb,
                                                  const int* __restrict__ fb,
                                                  int* __restrict__ offs,
                                                  int* __restrict__ edges,
                                                  unsigned int* __restrict__ bar) {
  const int blk = blockIdx.x;   // batch
  const int tid = threadIdx.x;  // 0..511 (one edge per thread)
  __shared__ int cnt[256], sc[256], cur[256];
  if (tid < ND) bar[tid * 16 + blk] = 0;   // zero this batch's 8 barrier slots
  if (tid < 256) cnt[tid] = 0;
  __syncthreads();
  const int n = tid >> 1, bit = tid & 1;
  const int tgt = bit ? fb[blk * NN + n] : tb[blk * NN + n];
  atomicAdd(&cnt[tgt], 1);
  __syncthreads();
  if (tid < 256) sc[tid] = cnt[tid];
  __syncthreads();
  for (int ofs = 1; ofs < 256; ofs <<= 1) {
    int t2 = (tid < 256 && tid >= ofs) ? sc[tid - ofs] : 0;
    __syncthreads();
    if (tid < 256) sc[tid] += t2;
    __syncthreads();
  }
  if (tid < 256) { offs[blk * NN + tid] = blk * 2 * NN + sc[tid] - cnt[tid]; cur[tid] = 0; }
  if (blk == 0 && tid == 0) offs[MM] = 2 * MM;
  __syncthreads();
  int lpos = sc[tgt] - cnt[tgt] + atomicAdd(&cur[tgt], 1);
  edges[blk * 2 * NN + lpos] = (n << 1) | bit;
}

// blocks 0..767: weight swizzle -> bf16 B-fragment order
// blocks 768..892: XW0 vocab table, G-INTERLEAVED layout:
//   tab[v*512 + w*64 + n*4 + g]  for original gate col c=(w+8g)*16+n
__global__ __launch_bounds__(256) void prep_kernel(
    const float* __restrict__ Wh0, const float* __restrict__ Wi1, const float* __restrict__ Wh1,
    const float* __restrict__ embed, const float* __restrict__ Wi0, const float* __restrict__ b0,
    unsigned short* __restrict__ swz, float* __restrict__ tab) {
  const int blk = blockIdx.x;
  const int tid = threadIdx.x;
  if (blk < 768) {
    int i = blk * 256 + tid;  // 0..196607
    int mtx = i >> 16, ii = i & 65535;
    const float* W = (mtx == 0) ? Wh0 : (mtx == 1) ? Wi1 : Wh1;
    int j = ii & 7, ln = (ii >> 3) & 63, kb = (ii >> 9) & 3, ct = ii >> 11;
    int n = ln & 15, q = ln >> 4;
    swz[i] = f2bu(W[(kb * 32 + q * 8 + j) * CC + ct * 16 + n]);
    return;
  }
  // XW0: tab[v] = embed[v]@Wi0 + b0; 125 blocks x 8 rows = 1000 rows
  const int v0 = (blk - 768) * 8;
  __shared__ float A[8][HH];
  for (int s = tid; s < 8 * HH; s += 256) {
    int r = s >> 7, k = s & 127;
    A[r][k] = embed[(size_t)(v0 + r) * HH + k];
  }
  __syncthreads();
  const int j = tid;  // gate col 0..255 (and j+256 for the second half)
  float za[8], zb[8];
  {
    float ba = b0[j], bbv = b0[j + 256];
#pragma unroll
    for (int r = 0; r < 8; ++r) { za[r] = ba; zb[r] = bbv; }
  }
#pragma unroll 4
  for (int k = 0; k < HH; ++k) {
    float wa = Wi0[k * CC + j], wb = Wi0[k * CC + j + 256];
#pragma unroll
    for (int r = 0; r < 8; ++r) { za[r] += A[r][k] * wa; zb[r] += A[r][k] * wb; }
  }
  // g-interleaved write: c=j -> T=j>>4 (0..15), g=T>>3 in {0,1}; c=j+256 -> g+2
  const int T = j >> 4, nn2 = j & 15;
  const int base1 = (T & 7) * 64 + nn2 * 4 + (T >> 3);
#pragma unroll
  for (int r = 0; r < 8; ++r) {
    tab[(size_t)(v0 + r) * CC + base1] = za[r];
    tab[(size_t)(v0 + r) * CC + base1 + 2] = zb[r];
  }
}

// ---------------- fused TWO-step kernel ----------------
// Dispatch d runs steps (2d, 2d+1) with a per-batch LLC barrier at the
// midpoint: state/branch-weight handoff via relaxed agent-scope (sc1)
// accesses, publish = __syncthreads (compiler drains vmcnt per wave) +
// relaxed add; consume = bounded relaxed spin. Everything else is the proven
// round-13/14 step body (tvAll preload, 1 barrier/token, 2-deep gather).
// Halves the dependent-dispatch count: 16 -> 8.

__global__ __launch_bounds__(512) void step2_kernel(
    float* __restrict__ Sc0g, float* __restrict__ Sh0g,
    float* __restrict__ Sc1g, float* __restrict__ Sh1g,
    unsigned int* __restrict__ PA, unsigned int* __restrict__ PB,
    float* __restrict__ w2A, float* __restrict__ w2B,
    const int* __restrict__ offs, const int* __restrict__ edges,
    const float* __restrict__ tab,
    const unsigned short* __restrict__ swzWh0, const unsigned short* __restrict__ swzWi1,
    const unsigned short* __restrict__ swzWh1, const float* __restrict__ b1,
    const float* __restrict__ Wb, const float* __restrict__ bb,
    const int* __restrict__ data, const int* __restrict__ exi,
    const int* __restrict__ steps, unsigned int* __restrict__ bar, int d) {
  const int B = blockIdx.x;
  const int b = (B & 7) | (((B >> 3) & 1) << 3);  // batch, pinned to XCD b%8
  const int g16 = B >> 4;                          // node-group 0..15 within batch
  const int row0 = b * NN + g16 * 16;
  const int sb = steps[b];
  const int s0 = 2 * d;
  {  // fully-dead fast path (batch finished before this dispatch)
    const bool aggA = (s0 >= 1) && ((s0 - 1) < sb);
    const bool lstmA = (s0 < sb);
    if (!aggA && !lstmA) return;
  }

  const int tid = threadIdx.x;
  const int w = tid >> 6;
  const int lane = tid & 63;
  const int n16 = lane & 15, qq = lane >> 4;
  const int kcol = w * 16 + n16;
  const int basePos = ((kcol >> 5) * 64 + ((kcol >> 3) & 3) * 16) * 8 + (kcol & 7);

  __shared__ float c0L[16 * SP], h0L[16 * SP], c1L[16 * SP], h1L[16 * SP];
  __shared__ __align__(16) unsigned short hA0[2][2048], hA1[2][2048];  // double-buffered
  __shared__ float exitP[512];
  __shared__ float ipL[16];
  __shared__ int toks[64];

  // ----- persistent loads: once per DISPATCH (shared by both halves),
  // issued before the first gather so their latency overlaps it
  s16x8 B0f[4][4], B1f[4][4];
  float b1v[4];
  const s16x8* pWh0 = (const s16x8*)swzWh0;
  const s16x8* pWh1 = (const s16x8*)swzWh1;
  const s16x8* pWi1 = (const s16x8*)swzWi1;
  if (s0 < sb) {  // lstmA (lstmB implies lstmA)
#pragma unroll
    for (int g = 0; g < 4; ++g) {
      int ci = w + 8 * g;
#pragma unroll
      for (int kb = 0; kb < 4; ++kb) {
        B0f[g][kb] = pWh0[(ci * 4 + kb) * 64 + lane];
        B1f[g][kb] = pWh1[(ci * 4 + kb) * 64 + lane];
      }
      b1v[g] = b1[ci * 16 + n16];
    }
    if (tid < 64) toks[tid] = data[(row0 + (tid >> 2)) * TT + (tid & 3)];
  }

  const int exnode = exi[b];
  const int exm = exnode - (g16 * 16);
  unsigned int* barslot = bar + d * 16 + b;

  for (int half = 0; half < 2; ++half) {
    const int s = s0 + half;
    const bool aggLive = (s >= 1) && ((s - 1) < sb);
    const bool lstmLive = (s < sb);
    const unsigned int* Pr = (s & 1) ? PB : PA;   // read parity
    unsigned int* Pw = (s & 1) ? PA : PB;         // write parity
    const float* w2R = (s & 1) ? w2B : w2A;
    float* w2W = (s & 1) ? w2A : w2B;

    if (half == 1) {
      // midpoint: wait for all 16 batch peers to publish step s0.
      // Bounded (~1 ms) so the kernel is finite no matter what.
      if (tid == 0) {
        unsigned long long t0 = __builtin_amdgcn_s_memrealtime();
        while (__hip_atomic_load(barslot, __ATOMIC_RELAXED, __HIP_MEMORY_SCOPE_AGENT) < 16u) {
          __builtin_amdgcn_s_sleep(8);
          if (__builtin_amdgcn_s_memrealtime() - t0 > 100000ull) break;
        }
      }
      asm volatile("" ::: "memory");
      __syncthreads();
    }

    // ----- prologue: aggregate previous step (16 nodes, 32 lanes each),
    // 2-deep pipelined; sc1 loads (LLC) — same latency class as the old
    // cross-dispatch path (L2 was invalidated at the boundary anyway).
    if (aggLive) {
      const int l = tid & 31;
      const int m = tid >> 5;
      const int node = row0 + m;
      const int beg = offs[node], end = offs[node + 1];
      const float* wR = w2R + (b << 9);  // {wt,wf} interleaved: index = rec
      float ac0[4] = {0,0,0,0}, ah0[4] = {0,0,0,0}, ac1[4] = {0,0,0,0}, ah1[4] = {0,0,0,0};
      float wsum = 0.f;
      float wvA = 0.f, wvB = 0.f;
      u64 a0q = 0, a1q = 0, a2q = 0, a3q = 0;
      u64 b0q = 0, b1q = 0, b2q = 0, b3q = 0;
      if (beg < end) {
        int rec = edges[beg];
        wvA = ldf_llc(&wR[rec]);
        const u64* pr = (const u64*)(Pr + (size_t)((b << 8) + (rec >> 1)) * 256 + 8 * l);
        a0q = ld64_llc(pr + 0); a1q = ld64_llc(pr + 1);
        a2q = ld64_llc(pr + 2); a3q = ld64_llc(pr + 3);
      }
      if (beg + 1 < end) {
        int rec = edges[beg + 1];
        wvB = ldf_llc(&wR[rec]);
        const u64* pr = (const u64*)(Pr + (size_t)((b << 8) + (rec >> 1)) * 256 + 8 * l);
        b0q = ld64_llc(pr + 0); b1q = ld64_llc(pr + 1);
        b2q = ld64_llc(pr + 2); b3q = ld64_llc(pr + 3);
      }
      for (int e = beg; e < end; e += 2) {
        float w0 = wvA; u64 c0q = a0q, c1q = a1q, c2q = a2q, c3q = a3q;
        float w1 = wvB; u64 d0q = b0q, d1q = b1q, d2q = b2q, d3q = b3q;
        const bool has1 = (e + 1 < end);
        if (e + 2 < end) {
          int rec = edges[e + 2];
          wvA = ldf_llc(&wR[rec]);
          const u64* pr = (const u64*)(Pr + (size_t)((b << 8) + (rec >> 1)) * 256 + 8 * l);
          a0q = ld64_llc(pr + 0); a1q = ld64_llc(pr + 1);
          a2q = ld64_llc(pr + 2); a3q = ld64_llc(pr + 3);
        }
        if (e + 3 < end) {
          int rec = edges[e + 3];
          wvB = ldf_llc(&wR[rec]);
          const u64* pr = (const u64*)(Pr + (size_t)((b << 8) + (rec >> 1)) * 256 + 8 * l);
          b0q = ld64_llc(pr + 0); b1q = ld64_llc(pr + 1);
          b2q = ld64_llc(pr + 2); b3q = ld64_llc(pr + 3);
        }
        {
          unsigned int x0 = (unsigned)c0q, x1 = (unsigned)(c0q >> 32);
          unsigned int x2 = (unsigned)c1q, x3 = (unsigned)(c1q >> 32);
          unsigned int y0 = (unsigned)c2q, y1 = (unsigned)(c2q >> 32);
          unsigned int y2 = (unsigned)c3q, y3 = (unsigned)(c3q >> 32);
          wsum += w0;
          ac0[0] += w0 * blo(x0); ac0[1] += w0 * bhi(x0);
          ac0[2] += w0 * blo(x1); ac0[3] += w0 * bhi(x1);
          ah0[0] += w0 * blo(x2); ah0[1] += w0 * bhi(x2);
          ah0[2] += w0 * blo(x3); ah0[3] += w0 * bhi(x3);
          ac1[0] += w0 * blo(y0); ac1[1] += w0 * bhi(y0);
          ac1[2] += w0 * blo(y1); ac1[3] += w0 * bhi(y1);
          ah1[0] += w0 * blo(y2); ah1[1] += w0 * bhi(y2);
          ah1[2] += w0 * blo(y3); ah1[3] += w0 * bhi(y3);
        }
        if (has1) {
          unsigned int x0 = (unsigned)d0q, x1 = (unsigned)(d0q >> 32);
          unsigned int x2 = (unsigned)d1q, x3 = (unsigned)(d1q >> 32);
          unsigned int y0 = (unsigned)d2q, y1 = (unsigned)(d2q >> 32);
          unsigned int y2 = (unsigned)d3q, y3 = (unsigned)(d3q >> 32);
          wsum += w1;
          ac0[0] += w1 * blo(x0); ac0[1] += w1 * bhi(x0);
          ac0[2] += w1 * blo(x1); ac0[3] += w1 * bhi(x1);
          ah0[0] += w1 * blo(x2); ah0[1] += w1 * bhi(x2);
          ah0[2] += w1 * blo(x3); ah0[3] += w1 * bhi(x3);
          ac1[0] += w1 * blo(y0); ac1[1] += w1 * bhi(y0);
          ac1[2] += w1 * blo(y1); ac1[3] += w1 * bhi(y1);
          ah1[0] += w1 * blo(y2); ah1[1] += w1 * bhi(y2);
          ah1[2] += w1 * blo(y3); ah1[3] += w1 * bhi(y3);
        }
      }
      float inv = 1.0f / (wsum + 1e-7f);
      float4 o0 = { ac0[0]*inv, ac0[1]*inv, ac0[2]*inv, ac0[3]*inv };
      float4 o1 = { ah0[0]*inv, ah0[1]*inv, ah0[2]*inv, ah0[3]*inv };
      float4 o2 = { ac1[0]*inv, ac1[1]*inv, ac1[2]*inv, ac1[3]*inv };
      float4 o3 = { ah1[0]*inv, ah1[1]*inv, ah1[2]*inv, ah1[3]*inv };
      ((float4*)c0L)[m * (SP / 4) + l] = o0;
      ((float4*)h0L)[m * (SP / 4) + l] = o1;
      ((float4*)c1L)[m * (SP / 4) + l] = o2;
      ((float4*)h1L)[m * (SP / 4) + l] = o3;
      if (l == 0) ipL[m] = wsum;
      if (!lstmLive) {  // batch death: persist exact f32 state for final_kernel
        ((float4*)Sc0g)[node * 32 + l] = o0;
        ((float4*)Sh0g)[node * 32 + l] = o1;
        ((float4*)Sc1g)[node * 32 + l] = o2;
        ((float4*)Sh1g)[node * 32 + l] = o3;
      }
    } else {
      // step 0: zero states, initial ip = [node==0]
      for (int i2 = tid; i2 < 16 * HH; i2 += 512) {
        int m = i2 >> 7, k = i2 & 127;
        c0L[m * SP + k] = 0.f; h0L[m * SP + k] = 0.f;
        c1L[m * SP + k] = 0.f; h1L[m * SP + k] = 0.f;
      }
      if (tid < 16) ipL[tid] = (((row0 + tid) & (NN - 1)) == 0) ? 1.0f : 0.0f;
    }
    if (!lstmLive) return;  // batch-uniform death; peers also return, no waiter

    __syncthreads();  // prologue state + toks visible

    // ALL tokens' tab rows preloaded: 16 independent dwordx4 (16-deep MLP);
    // drained once at the "fragments ready" barrier.
    const f32x4* ptab = (const f32x4*)tab;  // g-interleaved: [tok][w][n16][g]
    f32x4 tvAll[4][4];
#pragma unroll
    for (int t = 0; t < TT; ++t)
#pragma unroll
      for (int r = 0; r < 4; ++r)
        tvAll[t][r] = ptab[(size_t)toks[(qq * 4 + r) * 4 + t] * (CC / 4) + w * 16 + n16];

    // pristine exit-row copy
    if (exm >= 0 && exm < 16 && tid < 128) {
      exitP[tid] = c0L[exm * SP + tid];
      exitP[128 + tid] = h0L[exm * SP + tid];
      exitP[256 + tid] = c1L[exm * SP + tid];
      exitP[384 + tid] = h1L[exm * SP + tid];
    }

    // c-state into registers; build bf16 h A-fragments into buffer 0
    float c0r[4], c1r[4], h0r[4], h1r[4];
#pragma unroll
    for (int r = 0; r < 4; ++r) {
      int m = qq * 4 + r;
      c0r[r] = c0L[m * SP + kcol];
      c1r[r] = c1L[m * SP + kcol];
      h0r[r] = h0L[m * SP + kcol];
      h1r[r] = h1L[m * SP + kcol];
      hA0[0][basePos + m * 8] = f2bu(h0r[r]);
      hA1[0][basePos + m * 8] = f2bu(h1r[r]);
    }
    __syncthreads();  // fragments ready (drains the tab preload once)

    int cur = 0;
#pragma unroll
    for (int t = 0; t < TT; ++t) {
      const int nxt = cur ^ 1;
      const s16x8* hA0c = (const s16x8*)hA0[cur];
      s16x8 a0[4];
#pragma unroll
      for (int kb = 0; kb < 4; ++kb) a0[kb] = hA0c[kb * 64 + lane];
      f32x4 d0[4];
#pragma unroll
      for (int g = 0; g < 4; ++g)
#pragma unroll
        for (int r = 0; r < 4; ++r)
          d0[g][r] = tvAll[t][r][g];

      // layer 0 MFMA: z = tab(+b0) + h0 @ Wh0
#pragma unroll
      for (int g = 0; g < 4; ++g)
#pragma unroll
        for (int kb = 0; kb < 4; ++kb)
          d0[g] = __builtin_amdgcn_mfma_f32_16x16x32_bf16(a0[kb], B0f[g][kb], d0[g], 0, 0, 0);

      // gates 0; new h0 frags -> OTHER buffer
#pragma unroll
      for (int r = 0; r < 4; ++r) {
        float cn = sigf(d0[1][r]) * c0r[r] + sigf(d0[0][r]) * tanhr(d0[2][r]);
        float hn = sigf(d0[3][r]) * tanhr(cn);
        c0r[r] = cn; h0r[r] = hn;
        hA0[nxt][basePos + (qq * 4 + r) * 8] = f2bu(hn);
      }
      __syncthreads();  // SINGLE barrier: h0(t) visible AND h1(t-1) visible

      // layer 1: a1a from new h0, a1b from current h1 (read AFTER the barrier)
      const s16x8* hA0n = (const s16x8*)hA0[nxt];
      const s16x8* hA1c = (const s16x8*)hA1[cur];
      s16x8 a1a[4], a1b[4];
#pragma unroll
      for (int kb = 0; kb < 4; ++kb) {
        a1a[kb] = hA0n[kb * 64 + lane];
        a1b[kb] = hA1c[kb * 64 + lane];
      }
      f32x4 d1[4];
#pragma unroll
      for (int g = 0; g < 4; ++g) {
        int ci = w + 8 * g;
        s16x8 wi[4];
#pragma unroll
        for (int kb = 0; kb < 4; ++kb) wi[kb] = pWi1[(ci * 4 + kb) * 64 + lane];
        f32x4 dd = { b1v[g], b1v[g], b1v[g], b1v[g] };
#pragma unroll
        for (int kb = 0; kb < 4; ++kb)
          dd = __builtin_amdgcn_mfma_f32_16x16x32_bf16(a1a[kb], wi[kb], dd, 0, 0, 0);
#pragma unroll
        for (int kb = 0; kb < 4; ++kb)
          dd = __builtin_amdgcn_mfma_f32_16x16x32_bf16(a1b[kb], B1f[g][kb], dd, 0, 0, 0);
        d1[g] = dd;
      }

      // gates 1; new h1 frags -> OTHER buffer (t=TT-1 write dead -> skipped)
#pragma unroll
      for (int r = 0; r < 4; ++r) {
        float cn = sigf(d1[1][r]) * c1r[r] + sigf(d1[0][r]) * tanhr(d1[2][r]);
        float hn = sigf(d1[3][r]) * tanhr(cn);
        c1r[r] = cn; h1r[r] = hn;
        if (t + 1 < TT) hA1[nxt][basePos + (qq * 4 + r) * 8] = f2bu(hn);
      }
      cur = nxt;
    }

    // epilogue: regs -> LDS
#pragma unroll
    for (int r = 0; r < 4; ++r) {
      int m = qq * 4 + r;
      c0L[m * SP + kcol] = c0r[r];
      h0L[m * SP + kcol] = h0r[r];
      c1L[m * SP + kcol] = c1r[r];
      h1L[m * SP + kcol] = h1r[r];
    }
    __syncthreads();

    // branch softmax (32 threads/row); exit row uses pristine copy
    {
      const int m = tid >> 5, sub = tid & 31;
      const int row = row0 + m;
      const bool isExit = (m == exm);
      float z0 = 0.f, z1 = 0.f;
#pragma unroll
      for (int u = 0; u < 16; ++u) {
        int k = u * 32 + sub;
        int seg = k >> 7, kk = k & 127;
        float fk;
        if (isExit) {
          fk = exitP[seg * 128 + kk];
        } else {
          fk = (seg == 0) ? c0L[m * SP + kk] : (seg == 1) ? h0L[m * SP + kk]
             : (seg == 2) ? c1L[m * SP + kk] : h1L[m * SP + kk];
        }
        z0 += fk * Wb[2 * k];
        z1 += fk * Wb[2 * k + 1];
      }
#pragma unroll
      for (int off = 16; off >= 1; off >>= 1) {
        z0 += __shfl_xor(z0, off);
        z1 += __shfl_xor(z1, off);
      }
      if (sub == 0) {
        z0 += bb[0]; z1 += bb[1];
        float mx = fmaxf(z0, z1);
        float e0 = __expf(z0 - mx), e1 = __expf(z1 - mx);
        float inv = 1.0f / (e0 + e1);
        float ipv = ipL[m];
        float wt = e0 * inv * ipv, wf = e1 * inv * ipv;
        u64 pk = ((u64)__builtin_bit_cast(unsigned int, wf) << 32)
               | __builtin_bit_cast(unsigned int, wt);
        st64_llc((u64*)&w2W[2 * row], pk);  // interleaved {wt,wf}, LLC
      }
    }

    // writeout: pack to bf16; sc1 u64 stores; exit row from pristine copy
    {
      const int m = tid >> 5, l = tid & 31;
      const bool ex = (m == exm);
      const int grow = row0 + m;
      float f0[4], f1[4], f2[4], f3[4];
#pragma unroll
      for (int i = 0; i < 4; ++i) {
        int k = 4 * l + i;
        f0[i] = ex ? exitP[k] : c0L[m * SP + k];
        f1[i] = ex ? exitP[128 + k] : h0L[m * SP + k];
        f2[i] = ex ? exitP[256 + k] : c1L[m * SP + k];
        f3[i] = ex ? exitP[384 + k] : h1L[m * SP + k];
      }
      u64* pw = (u64*)(Pw + (size_t)grow * 256 + 8 * l);
      st64_llc(pw + 0, ((u64)packh(f0[2], f0[3]) << 32) | packh(f0[0], f0[1]));
      st64_llc(pw + 1, ((u64)packh(f1[2], f1[3]) << 32) | packh(f1[0], f1[1]));
      st64_llc(pw + 2, ((u64)packh(f2[2], f2[3]) << 32) | packh(f2[0], f2[1]));
      st64_llc(pw + 3, ((u64)packh(f3[2], f3[3]) << 32) | packh(f3[0], f3[1]));
    }

    if (half == 0) {
      // publish step s0: __syncthreads makes every wave drain its vmcnt
      // (compiler emits the full waitcnt before s_barrier), then relaxed add.
      __syncthreads();
      if (tid == 0) {
        asm volatile("s_waitcnt vmcnt(0)" ::: "memory");
        __hip_atomic_fetch_add(barslot, 1u, __ATOMIC_RELAXED, __HIP_MEMORY_SCOPE_AGENT);
      }
    }
  }
}

// logits: 64 blocks (16 batches x 4 col-tiles of 250), 256 threads, 1 output/thread
__global__ void final_kernel(const float* __restrict__ Sc0, const float* __restrict__ Sh0,
                             const float* __restrict__ Sc1, const float* __restrict__ Sh1,
                             const int* __restrict__ exi, const float* __restrict__ Wo,
                             const float* __restrict__ bo, float* __restrict__ out) {
  const int b = blockIdx.x >> 2;
  const int vt = blockIdx.x & 3;
  const int tid = threadIdx.x;  // 256
  __shared__ float f[512];
  int row = b * NN + exi[b];
  if (tid < 128) {
    size_t g = (size_t)row * HH + tid;
    f[tid] = Sc0[g];
    f[128 + tid] = Sh0[g];
    f[256 + tid] = Sc1[g];
    f[384 + tid] = Sh1[g];
  }
  __syncthreads();
  if (tid < 250) {
    int v = vt * 250 + tid;
    float acc = bo[v];
#pragma unroll 8
    for (int k = 0; k < 512; ++k) acc += f[k] * Wo[(size_t)k * OUTV + v];
    out[b * OUTV + v] = acc;
  }
}

// distinct failure signature if workspace too small: out := 0 -> err == ref absmax
__global__ void zero_out_kernel(float* __restrict__ out, int n) {
  int i = blockIdx.x * blockDim.x + threadIdx.x;
  if (i < n) out[i] = 0.0f;
}

// ---------------- host orchestration ----------------

extern "C" void kernel_launch(void* const* d_in, const int* in_sizes, int n_in,
                              void* d_out, int out_size, void* d_ws, size_t ws_size,
                              hipStream_t stream) {
  const int* data = (const int*)d_in[0];
  const int* tb   = (const int*)d_in[1];
  const int* fb   = (const int*)d_in[2];
  const int* exi  = (const int*)d_in[3];
  const int* steps = (const int*)d_in[4];
  const float* embed = (const float*)d_in[5];
  const float* Wi = (const float*)d_in[6];   // (L,H,4H)
  const float* Wh = (const float*)d_in[7];   // (L,H,4H)
  const float* bl = (const float*)d_in[8];   // (L,4H)
  const float* Wb = (const float*)d_in[9];   // (2LH,2)
  const float* bb = (const float*)d_in[10];  // (2,)
  const float* Wo = (const float*)d_in[11];  // (2LH,OUT)
  const float* bo = (const float*)d_in[12];  // (OUT,)
  float* out = (float*)d_out;

  const float* Wi0 = Wi;
  const float* Wi1 = Wi + HH * CC;
  const float* Wh0 = Wh;
  const float* Wh1 = Wh + HH * CC;
  const float* b0 = bl;
  const float* b1 = bl + CC;

  float* ws = (float*)d_ws;
  size_t off = 0;
  float* tab = ws + off;  off += (size_t)1024 * CC;        // 2 MB
  float* Sc0 = ws + off;  off += (size_t)MM * HH;          // death/final f32 bufs
  float* Sh0 = ws + off;  off += (size_t)MM * HH;
  float* Sc1 = ws + off;  off += (size_t)MM * HH;
  float* Sh1 = ws + off;  off += (size_t)MM * HH;
  unsigned int* PA = (unsigned int*)(ws + off); off += (size_t)MM * 256;  // packed state A
  unsigned int* PB = (unsigned int*)(ws + off); off += (size_t)MM * 256;  // packed state B
  unsigned short* swz = (unsigned short*)(ws + off); off += 3 * 32768;    // 3x65536 bf16
  float* w2A = ws + off;  off += 2 * MM;   // interleaved {wt,wf}, parity A
  float* w2B = ws + off;  off += 2 * MM;   // interleaved {wt,wf}, parity B
  int* offs  = (int*)(ws + off); off += MM + 16;
  int* edges = (int*)(ws + off); off += 2 * MM;
  unsigned int* bar = (unsigned int*)(ws + off); off += ND * 16;
  (void)in_sizes; (void)n_in; (void)out_size;

  if (ws_size < off * sizeof(float)) {
    zero_out_kernel<<<(BB * OUTV + 255) / 256, 256, 0, stream>>>(out, BB * OUTV);
    return;
  }

  unsigned short* swzWh0 = swz;
  unsigned short* swzWi1 = swz + 65536;
  unsigned short* swzWh1 = swz + 2 * 65536;

  csr_kernel<<<BB, 512, 0, stream>>>(tb, fb, offs, edges, bar);
  prep_kernel<<<893, 256, 0, stream>>>(Wh0, Wi1, Wh1, embed, Wi0, b0, swz, tab);

  // 8 fused dispatches: dispatch d = steps (2d, 2d+1); per-batch LLC barrier
  // at the midpoint (slot bar[d*16+b]).
  for (int d = 0; d < ND; ++d) {
    step2_kernel<<<MM / 16, 512, 0, stream>>>(
        Sc0, Sh0, Sc1, Sh1, PA, PB, w2A, w2B,
        offs, edges, tab, swzWh0, swzWi1, swzWh1, b1, Wb, bb,
        data, exi, steps, bar, d);
  }
  final_kernel<<<BB * 4, 256, 0, stream>>>(Sc0, Sh0, Sc1, Sh1, exi, Wo, bo, out);
}

// Round 16
// 506.107 us; speedup vs baseline: 2.1429x; 2.1429x over previous
//
#include <hip/hip_runtime.h>
#include <hip/hip_bf16.h>
#include <stdint.h>
#include <stddef.h>

static constexpr int BB = 16, NN = 256, TT = 4, HH = 128;
static constexpr int MM = BB * NN;     // 4096 rows
static constexpr int CC = 512;         // 4*H gate width
static constexpr int OUTV = 1000;
static constexpr int MAXS = 15;
static constexpr int SP = 132;         // f32 state row pitch in LDS

typedef float f32x4 __attribute__((ext_vector_type(4)));
typedef short s16x8 __attribute__((ext_vector_type(8)));

__device__ __forceinline__ float sigf(float x) { return 1.0f / (1.0f + __expf(-x)); }
__device__ __forceinline__ float tanhr(float x) { return 2.0f / (1.0f + __expf(-2.0f * x)) - 1.0f; }
__device__ __forceinline__ unsigned short f2bu(float a) {
  return __builtin_bit_cast(unsigned short, __float2bfloat16(a));
}
__device__ __forceinline__ unsigned int packh(float a, float b) {
  return (unsigned int)f2bu(a) | ((unsigned int)f2bu(b) << 16);
}
__device__ __forceinline__ float blo(unsigned int u) { return __builtin_bit_cast(float, u << 16); }
__device__ __forceinline__ float bhi(unsigned int u) { return __builtin_bit_cast(float, u & 0xffff0000u); }

// ---------------- setup kernel (merged csr + prep: ONE dispatch) ----------------
// Validated in rounds 8/10 (passed, exact absmax; round 11 cleared it of the
// live-step regression). blocks 0..15: per-batch CSR; 16..399: weight swizzle;
// 400..524: XW0 vocab table, G-INTERLEAVED tab[v*512 + w*64 + n*4 + g].
__global__ __launch_bounds__(512) void setup_kernel(
    const int* __restrict__ tb, const int* __restrict__ fb,
    int* __restrict__ offs, int* __restrict__ edges,
    const float* __restrict__ Wh0, const float* __restrict__ Wi1, const float* __restrict__ Wh1,
    const float* __restrict__ embed, const float* __restrict__ Wi0, const float* __restrict__ b0,
    unsigned short* __restrict__ swz, float* __restrict__ tab) {
  const int blk = blockIdx.x;
  const int tid = threadIdx.x;
  if (blk < 16) {
    // CSR for batch blk: one edge per thread (512 edges)
    __shared__ int cnt[256], sc[256], cur[256];
    if (tid < 256) cnt[tid] = 0;
    __syncthreads();
    const int n = tid >> 1, bit = tid & 1;
    const int tgt = bit ? fb[blk * NN + n] : tb[blk * NN + n];
    atomicAdd(&cnt[tgt], 1);
    __syncthreads();
    if (tid < 256) sc[tid] = cnt[tid];
    __syncthreads();
    for (int ofs = 1; ofs < 256; ofs <<= 1) {
      int t2 = (tid < 256 && tid >= ofs) ? sc[tid - ofs] : 0;
      __syncthreads();
      if (tid < 256) sc[tid] += t2;
      __syncthreads();
    }
    if (tid < 256) { offs[blk * NN + tid] = blk * 2 * NN + sc[tid] - cnt[tid]; cur[tid] = 0; }
    if (blk == 0 && tid == 0) offs[MM] = 2 * MM;
    __syncthreads();
    int lpos = sc[tgt] - cnt[tgt] + atomicAdd(&cur[tgt], 1);
    edges[blk * 2 * NN + lpos] = (n << 1) | bit;
  } else if (blk < 400) {
    int i = (blk - 16) * 512 + tid;  // 0..196607
    int mtx = i >> 16, ii = i & 65535;
    const float* W = (mtx == 0) ? Wh0 : (mtx == 1) ? Wi1 : Wh1;
    int j = ii & 7, ln = (ii >> 3) & 63, kb = (ii >> 9) & 3, ct = ii >> 11;
    int n = ln & 15, q = ln >> 4;
    swz[i] = f2bu(W[(kb * 32 + q * 8 + j) * CC + ct * 16 + n]);
  } else {
    // tab: 8 vocab rows per block, one gate column per thread (512 cols)
    const int v0 = (blk - 400) * 8;
    __shared__ float A[8][HH];
    for (int s2 = tid; s2 < 8 * HH; s2 += 512) {
      int r = s2 >> 7, k = s2 & 127;
      A[r][k] = embed[(size_t)(v0 + r) * HH + k];
    }
    __syncthreads();
    const int j = tid;  // 0..511
    float z[8];
    {
      float bj = b0[j];
#pragma unroll
      for (int r = 0; r < 8; ++r) z[r] = bj;
    }
#pragma unroll 4
    for (int k = 0; k < HH; ++k) {
      float wv = Wi0[k * CC + j];
#pragma unroll
      for (int r = 0; r < 8; ++r) z[r] += A[r][k] * wv;
    }
    // g-interleaved write: T=j>>4, n=j&15 -> base=(T&7)*64+n*4+(T>>3)
    const int T = j >> 4, nn2 = j & 15;
    const int base = (T & 7) * 64 + nn2 * 4 + (T >> 3);
#pragma unroll
    for (int r = 0; r < 8; ++r) tab[(size_t)(v0 + r) * CC + base] = z[r];
  }
}

// ---------------- fused per-step kernel (round-14 proven, 510.0us) ----------------
// 16 rows/block, 512 threads = 8 waves. tvAll full tab preload (16-deep MLP,
// drained once/step), 1 barrier/token, 2-deep-pipelined gather, interleaved
// {wt,wf} branch weights, plain loads/stores (L2-cached; kernel boundaries
// provide coherence — round 15 proved software LLC handoff costs 2.5x more).

__global__ __launch_bounds__(512) void step_kernel(
    float* __restrict__ Sc0g, float* __restrict__ Sh0g,
    float* __restrict__ Sc1g, float* __restrict__ Sh1g,
    const unsigned int* __restrict__ Pr, unsigned int* __restrict__ Pw,
    const float* __restrict__ w2R, float* __restrict__ w2W,
    const int* __restrict__ offs, const int* __restrict__ edges,
    const float* __restrict__ tab,
    const unsigned short* __restrict__ swzWh0, const unsigned short* __restrict__ swzWi1,
    const unsigned short* __restrict__ swzWh1, const float* __restrict__ b1,
    const float* __restrict__ Wb, const float* __restrict__ bb,
    const int* __restrict__ data, const int* __restrict__ exi,
    const int* __restrict__ steps, int step) {
  const int B = blockIdx.x;
  const int b = (B & 7) | (((B >> 3) & 1) << 3);  // batch, pinned to XCD b%8
  const int g16 = B >> 4;                          // node-group 0..15 within batch
  const int row0 = b * NN + g16 * 16;
  const int sb = steps[b];
  const bool aggLive = (step >= 1) && ((step - 1) < sb);
  const bool lstmLive = (step < sb);
  if (!aggLive && !lstmLive) return;

  const int tid = threadIdx.x;
  const int w = tid >> 6;
  const int lane = tid & 63;
  const int n16 = lane & 15, qq = lane >> 4;
  const int kcol = w * 16 + n16;
  const int basePos = ((kcol >> 5) * 64 + ((kcol >> 3) & 3) * 16) * 8 + (kcol & 7);

  __shared__ float c0L[16 * SP], h0L[16 * SP], c1L[16 * SP], h1L[16 * SP];
  __shared__ __align__(16) unsigned short hA0[2][2048], hA1[2][2048];  // double-buffered
  __shared__ float exitP[512];
  __shared__ float ipL[16];
  __shared__ int toks[64];

  // ----- HOISTED persistent loads: issued before the gather so they overlap it
  s16x8 B0f[4][4], B1f[4][4];
  float b1v[4];
  const s16x8* pWh0 = (const s16x8*)swzWh0;
  const s16x8* pWh1 = (const s16x8*)swzWh1;
  const s16x8* pWi1 = (const s16x8*)swzWi1;
  if (lstmLive) {
#pragma unroll
    for (int g = 0; g < 4; ++g) {
      int ci = w + 8 * g;
#pragma unroll
      for (int kb = 0; kb < 4; ++kb) {
        B0f[g][kb] = pWh0[(ci * 4 + kb) * 64 + lane];
        B1f[g][kb] = pWh1[(ci * 4 + kb) * 64 + lane];
      }
      b1v[g] = b1[ci * 16 + n16];
    }
    if (tid < 64) toks[tid] = data[(row0 + (tid >> 2)) * TT + (tid & 3)];
  }

  // ----- prologue: aggregate previous step (16 nodes, 32 lanes each),
  // software-pipelined TWO edges deep; single-load interleaved branch weights
  if (aggLive) {
    const int l = tid & 31;
    const int m = tid >> 5;
    const int node = row0 + m;
    const int beg = offs[node], end = offs[node + 1];
    const float* wR = w2R + (b << 9);  // {wt,wf} interleaved: index = rec
    float ac0[4] = {0,0,0,0}, ah0[4] = {0,0,0,0}, ac1[4] = {0,0,0,0}, ah1[4] = {0,0,0,0};
    float wsum = 0.f;
    float wvA = 0.f, wvB = 0.f;
    uint4 pA0 = {0,0,0,0}, pA1 = {0,0,0,0}, pB0 = {0,0,0,0}, pB1 = {0,0,0,0};
    if (beg < end) {
      int rec = edges[beg];
      wvA = wR[rec];
      const uint4* pr = (const uint4*)(Pr + (size_t)((b << 8) + (rec >> 1)) * 256 + 8 * l);
      pA0 = pr[0]; pA1 = pr[1];
    }
    if (beg + 1 < end) {
      int rec = edges[beg + 1];
      wvB = wR[rec];
      const uint4* pr = (const uint4*)(Pr + (size_t)((b << 8) + (rec >> 1)) * 256 + 8 * l);
      pB0 = pr[0]; pB1 = pr[1];
    }
    for (int e = beg; e < end; e += 2) {
      float w0 = wvA; uint4 u00 = pA0, u01 = pA1;
      float w1 = wvB; uint4 u10 = pB0, u11 = pB1;
      const bool has1 = (e + 1 < end);
      if (e + 2 < end) {  // prefetch two edges ahead
        int rec = edges[e + 2];
        wvA = wR[rec];
        const uint4* pr = (const uint4*)(Pr + (size_t)((b << 8) + (rec >> 1)) * 256 + 8 * l);
        pA0 = pr[0]; pA1 = pr[1];
      }
      if (e + 3 < end) {
        int rec = edges[e + 3];
        wvB = wR[rec];
        const uint4* pr = (const uint4*)(Pr + (size_t)((b << 8) + (rec >> 1)) * 256 + 8 * l);
        pB0 = pr[0]; pB1 = pr[1];
      }
      wsum += w0;
      ac0[0] += w0 * blo(u00.x); ac0[1] += w0 * bhi(u00.x);
      ac0[2] += w0 * blo(u00.y); ac0[3] += w0 * bhi(u00.y);
      ah0[0] += w0 * blo(u00.z); ah0[1] += w0 * bhi(u00.z);
      ah0[2] += w0 * blo(u00.w); ah0[3] += w0 * bhi(u00.w);
      ac1[0] += w0 * blo(u01.x); ac1[1] += w0 * bhi(u01.x);
      ac1[2] += w0 * blo(u01.y); ac1[3] += w0 * bhi(u01.y);
      ah1[0] += w0 * blo(u01.z); ah1[1] += w0 * bhi(u01.z);
      ah1[2] += w0 * blo(u01.w); ah1[3] += w0 * bhi(u01.w);
      if (has1) {
        wsum += w1;
        ac0[0] += w1 * blo(u10.x); ac0[1] += w1 * bhi(u10.x);
        ac0[2] += w1 * blo(u10.y); ac0[3] += w1 * bhi(u10.y);
        ah0[0] += w1 * blo(u10.z); ah0[1] += w1 * bhi(u10.z);
        ah0[2] += w1 * blo(u10.w); ah0[3] += w1 * bhi(u10.w);
        ac1[0] += w1 * blo(u11.x); ac1[1] += w1 * bhi(u11.x);
        ac1[2] += w1 * blo(u11.y); ac1[3] += w1 * bhi(u11.y);
        ah1[0] += w1 * blo(u11.z); ah1[1] += w1 * bhi(u11.z);
        ah1[2] += w1 * blo(u11.w); ah1[3] += w1 * bhi(u11.w);
      }
    }
    float inv = 1.0f / (wsum + 1e-7f);
    float4 o0 = { ac0[0]*inv, ac0[1]*inv, ac0[2]*inv, ac0[3]*inv };
    float4 o1 = { ah0[0]*inv, ah0[1]*inv, ah0[2]*inv, ah0[3]*inv };
    float4 o2 = { ac1[0]*inv, ac1[1]*inv, ac1[2]*inv, ac1[3]*inv };
    float4 o3 = { ah1[0]*inv, ah1[1]*inv, ah1[2]*inv, ah1[3]*inv };
    ((float4*)c0L)[m * (SP / 4) + l] = o0;
    ((float4*)h0L)[m * (SP / 4) + l] = o1;
    ((float4*)c1L)[m * (SP / 4) + l] = o2;
    ((float4*)h1L)[m * (SP / 4) + l] = o3;
    if (l == 0) ipL[m] = wsum;
    if (!lstmLive) {  // batch death: persist exact f32 state for final_kernel
      ((float4*)Sc0g)[node * 32 + l] = o0;
      ((float4*)Sh0g)[node * 32 + l] = o1;
      ((float4*)Sc1g)[node * 32 + l] = o2;
      ((float4*)Sh1g)[node * 32 + l] = o3;
    }
  } else {
    // step 0: zero states, initial ip = [node==0]
    for (int i2 = tid; i2 < 16 * HH; i2 += 512) {
      int m = i2 >> 7, k = i2 & 127;
      c0L[m * SP + k] = 0.f; h0L[m * SP + k] = 0.f;
      c1L[m * SP + k] = 0.f; h1L[m * SP + k] = 0.f;
    }
    if (tid < 16) ipL[tid] = (((row0 + tid) & (NN - 1)) == 0) ? 1.0f : 0.0f;
  }
  if (!lstmLive) return;  // block-uniform

  const int exnode = exi[b];
  const int exm = exnode - (g16 * 16);
  __syncthreads();  // prologue state + toks visible

  // ALL tokens' tab rows preloaded here: 16 independent dwordx4 (16-deep MLP).
  // Their latency overlaps the exitP copy + fragment build; drained once at
  // the "fragments ready" barrier.
  const f32x4* ptab = (const f32x4*)tab;  // g-interleaved: [tok][w][n16][g]
  f32x4 tvAll[4][4];
#pragma unroll
  for (int t = 0; t < TT; ++t)
#pragma unroll
    for (int r = 0; r < 4; ++r)
      tvAll[t][r] = ptab[(size_t)toks[(qq * 4 + r) * 4 + t] * (CC / 4) + w * 16 + n16];

  // pristine exit-row copy
  if (exm >= 0 && exm < 16 && tid < 128) {
    exitP[tid] = c0L[exm * SP + tid];
    exitP[128 + tid] = h0L[exm * SP + tid];
    exitP[256 + tid] = c1L[exm * SP + tid];
    exitP[384 + tid] = h1L[exm * SP + tid];
  }

  // c-state into registers; build bf16 h A-fragments into buffer 0
  float c0r[4], c1r[4], h0r[4], h1r[4];
#pragma unroll
  for (int r = 0; r < 4; ++r) {
    int m = qq * 4 + r;
    c0r[r] = c0L[m * SP + kcol];
    c1r[r] = c1L[m * SP + kcol];
    h0r[r] = h0L[m * SP + kcol];
    h1r[r] = h1L[m * SP + kcol];
    hA0[0][basePos + m * 8] = f2bu(h0r[r]);
    hA1[0][basePos + m * 8] = f2bu(h1r[r]);
  }
  __syncthreads();  // fragments ready (drains the tab preload once)

  int cur = 0;
#pragma unroll
  for (int t = 0; t < TT; ++t) {
    const int nxt = cur ^ 1;
    // layer 0: read a0 from current h0 buffer
    const s16x8* hA0c = (const s16x8*)hA0[cur];
    s16x8 a0[4];
#pragma unroll
    for (int kb = 0; kb < 4; ++kb) a0[kb] = hA0c[kb * 64 + lane];
    f32x4 d0[4];
#pragma unroll
    for (int g = 0; g < 4; ++g)
#pragma unroll
      for (int r = 0; r < 4; ++r)
        d0[g][r] = tvAll[t][r][g];

    // layer 0 MFMA: z = tab(+b0) + h0 @ Wh0
#pragma unroll
    for (int g = 0; g < 4; ++g)
#pragma unroll
      for (int kb = 0; kb < 4; ++kb)
        d0[g] = __builtin_amdgcn_mfma_f32_16x16x32_bf16(a0[kb], B0f[g][kb], d0[g], 0, 0, 0);

    // gates 0 in registers; new h0 frags -> OTHER buffer
#pragma unroll
    for (int r = 0; r < 4; ++r) {
      float cn = sigf(d0[1][r]) * c0r[r] + sigf(d0[0][r]) * tanhr(d0[2][r]);
      float hn = sigf(d0[3][r]) * tanhr(cn);
      c0r[r] = cn; h0r[r] = hn;
      hA0[nxt][basePos + (qq * 4 + r) * 8] = f2bu(hn);
    }
    __syncthreads();  // SINGLE barrier: h0(t) visible AND h1(t-1) visible

    // layer 1: a1a from new h0, a1b from current h1 (read AFTER the barrier)
    const s16x8* hA0n = (const s16x8*)hA0[nxt];
    const s16x8* hA1c = (const s16x8*)hA1[cur];
    s16x8 a1a[4], a1b[4];
#pragma unroll
    for (int kb = 0; kb < 4; ++kb) {
      a1a[kb] = hA0n[kb * 64 + lane];
      a1b[kb] = hA1c[kb * 64 + lane];
    }
    f32x4 d1[4];
#pragma unroll
    for (int g = 0; g < 4; ++g) {
      int ci = w + 8 * g;
      s16x8 wi[4];
#pragma unroll
      for (int kb = 0; kb < 4; ++kb) wi[kb] = pWi1[(ci * 4 + kb) * 64 + lane];
      f32x4 d = { b1v[g], b1v[g], b1v[g], b1v[g] };
#pragma unroll
      for (int kb = 0; kb < 4; ++kb)
        d = __builtin_amdgcn_mfma_f32_16x16x32_bf16(a1a[kb], wi[kb], d, 0, 0, 0);
#pragma unroll
      for (int kb = 0; kb < 4; ++kb)
        d = __builtin_amdgcn_mfma_f32_16x16x32_bf16(a1b[kb], B1f[g][kb], d, 0, 0, 0);
      d1[g] = d;
    }

    // gates 1 in registers; new h1 frags -> OTHER buffer (t=TT-1 write dead)
#pragma unroll
    for (int r = 0; r < 4; ++r) {
      float cn = sigf(d1[1][r]) * c1r[r] + sigf(d1[0][r]) * tanhr(d1[2][r]);
      float hn = sigf(d1[3][r]) * tanhr(cn);
      c1r[r] = cn; h1r[r] = hn;
      if (t + 1 < TT) hA1[nxt][basePos + (qq * 4 + r) * 8] = f2bu(hn);
    }
    cur = nxt;
  }

  // epilogue: regs -> LDS
#pragma unroll
  for (int r = 0; r < 4; ++r) {
    int m = qq * 4 + r;
    c0L[m * SP + kcol] = c0r[r];
    h0L[m * SP + kcol] = h0r[r];
    c1L[m * SP + kcol] = c1r[r];
    h1L[m * SP + kcol] = h1r[r];
  }
  __syncthreads();

  // branch softmax (32 threads/row); exit row uses pristine copy
  {
    const int m = tid >> 5, sub = tid & 31;
    const int row = row0 + m;
    const bool isExit = (m == exm);
    float z0 = 0.f, z1 = 0.f;
#pragma unroll
    for (int u = 0; u < 16; ++u) {
      int k = u * 32 + sub;
      int seg = k >> 7, kk = k & 127;
      float fk;
      if (isExit) {
        fk = exitP[seg * 128 + kk];
      } else {
        fk = (seg == 0) ? c0L[m * SP + kk] : (seg == 1) ? h0L[m * SP + kk]
           : (seg == 2) ? c1L[m * SP + kk] : h1L[m * SP + kk];
      }
      z0 += fk * Wb[2 * k];
      z1 += fk * Wb[2 * k + 1];
    }
#pragma unroll
    for (int off = 16; off >= 1; off >>= 1) {
      z0 += __shfl_xor(z0, off);
      z1 += __shfl_xor(z1, off);
    }
    if (sub == 0) {
      z0 += bb[0]; z1 += bb[1];
      float mx = fmaxf(z0, z1);
      float e0 = __expf(z0 - mx), e1 = __expf(z1 - mx);
      float inv = 1.0f / (e0 + e1);
      float ipv = ipL[m];
      float2 wp = { e0 * inv * ipv, e1 * inv * ipv };
      ((float2*)w2W)[row] = wp;  // interleaved {wt,wf}
    }
  }

  // writeout: pack to bf16, 2 x dwordx4 per lane; exit row from pristine copy
  {
    const int m = tid >> 5, l = tid & 31;
    const bool ex = (m == exm);
    const int grow = row0 + m;
    float f0[4], f1[4], f2[4], f3[4];
#pragma unroll
    for (int i = 0; i < 4; ++i) {
      int k = 4 * l + i;
      f0[i] = ex ? exitP[k] : c0L[m * SP + k];
      f1[i] = ex ? exitP[128 + k] : h0L[m * SP + k];
      f2[i] = ex ? exitP[256 + k] : c1L[m * SP + k];
      f3[i] = ex ? exitP[384 + k] : h1L[m * SP + k];
    }
    uint4 o0 = { packh(f0[0], f0[1]), packh(f0[2], f0[3]),
                 packh(f1[0], f1[1]), packh(f1[2], f1[3]) };
    uint4 o1 = { packh(f2[0], f2[1]), packh(f2[2], f2[3]),
                 packh(f3[0], f3[1]), packh(f3[2], f3[3]) };
    uint4* pw = (uint4*)(Pw + (size_t)grow * 256 + 8 * l);
    pw[0] = o0; pw[1] = o1;
  }
}

// logits: 64 blocks (16 batches x 4 col-tiles of 250), 256 threads, 1 output/thread
__global__ void final_kernel(const float* __restrict__ Sc0, const float* __restrict__ Sh0,
                             const float* __restrict__ Sc1, const float* __restrict__ Sh1,
                             const int* __restrict__ exi, const float* __restrict__ Wo,
                             const float* __restrict__ bo, float* __restrict__ out) {
  const int b = blockIdx.x >> 2;
  const int vt = blockIdx.x & 3;
  const int tid = threadIdx.x;  // 256
  __shared__ float f[512];
  int row = b * NN + exi[b];
  if (tid < 128) {
    size_t g = (size_t)row * HH + tid;
    f[tid] = Sc0[g];
    f[128 + tid] = Sh0[g];
    f[256 + tid] = Sc1[g];
    f[384 + tid] = Sh1[g];
  }
  __syncthreads();
  if (tid < 250) {
    int v = vt * 250 + tid;
    float acc = bo[v];
#pragma unroll 8
    for (int k = 0; k < 512; ++k) acc += f[k] * Wo[(size_t)k * OUTV + v];
    out[b * OUTV + v] = acc;
  }
}

// distinct failure signature if workspace too small: out := 0 -> err == ref absmax
__global__ void zero_out_kernel(float* __restrict__ out, int n) {
  int i = blockIdx.x * blockDim.x + threadIdx.x;
  if (i < n) out[i] = 0.0f;
}

// ---------------- host orchestration ----------------

extern "C" void kernel_launch(void* const* d_in, const int* in_sizes, int n_in,
                              void* d_out, int out_size, void* d_ws, size_t ws_size,
                              hipStream_t stream) {
  const int* data = (const int*)d_in[0];
  const int* tb   = (const int*)d_in[1];
  const int* fb   = (const int*)d_in[2];
  const int* exi  = (const int*)d_in[3];
  const int* steps = (const int*)d_in[4];
  const float* embed = (const float*)d_in[5];
  const float* Wi = (const float*)d_in[6];   // (L,H,4H)
  const float* Wh = (const float*)d_in[7];   // (L,H,4H)
  const float* bl = (const float*)d_in[8];   // (L,4H)
  const float* Wb = (const float*)d_in[9];   // (2LH,2)
  const float* bb = (const float*)d_in[10];  // (2,)
  const float* Wo = (const float*)d_in[11];  // (2LH,OUT)
  const float* bo = (const float*)d_in[12];  // (OUT,)
  float* out = (float*)d_out;

  const float* Wi0 = Wi;
  const float* Wi1 = Wi + HH * CC;
  const float* Wh0 = Wh;
  const float* Wh1 = Wh + HH * CC;
  const float* b0 = bl;
  const float* b1 = bl + CC;

  float* ws = (float*)d_ws;
  size_t off = 0;
  float* tab = ws + off;  off += (size_t)1024 * CC;        // 2 MB
  float* Sc0 = ws + off;  off += (size_t)MM * HH;          // death/final f32 bufs
  float* Sh0 = ws + off;  off += (size_t)MM * HH;
  float* Sc1 = ws + off;  off += (size_t)MM * HH;
  float* Sh1 = ws + off;  off += (size_t)MM * HH;
  unsigned int* PA = (unsigned int*)(ws + off); off += (size_t)MM * 256;  // packed state A
  unsigned int* PB = (unsigned int*)(ws + off); off += (size_t)MM * 256;  // packed state B
  unsigned short* swz = (unsigned short*)(ws + off); off += 3 * 32768;    // 3x65536 bf16
  float* w2A = ws + off;  off += 2 * MM;   // interleaved {wt,wf}, parity A
  float* w2B = ws + off;  off += 2 * MM;   // interleaved {wt,wf}, parity B
  int* offs  = (int*)(ws + off); off += MM + 16;
  int* edges = (int*)(ws + off); off += 2 * MM;
  (void)in_sizes; (void)n_in; (void)out_size;

  if (ws_size < off * sizeof(float)) {
    zero_out_kernel<<<(BB * OUTV + 255) / 256, 256, 0, stream>>>(out, BB * OUTV);
    return;
  }

  unsigned short* swzWh0 = swz;
  unsigned short* swzWi1 = swz + 65536;
  unsigned short* swzWh1 = swz + 2 * 65536;

  setup_kernel<<<525, 512, 0, stream>>>(tb, fb, offs, edges,
                                        Wh0, Wi1, Wh1, embed, Wi0, b0, swz, tab);

  // dispatch s: prologue aggregates step s-1 (reads other parity), LSTM writes parity s&1.
  for (int s = 0; s <= MAXS; ++s) {
    unsigned int* Pwp = (s & 1) ? PB : PA;
    const unsigned int* Prp = (s & 1) ? PA : PB;
    float* w2Wp = (s & 1) ? w2B : w2A;
    const float* w2Rp = (s & 1) ? w2A : w2B;
    step_kernel<<<MM / 16, 512, 0, stream>>>(
        Sc0, Sh0, Sc1, Sh1, Prp, Pwp,
        w2Rp, w2Wp,
        offs, edges, tab, swzWh0, swzWi1, swzWh1, b1, Wb, bb,
        data, exi, steps, s);
  }
  final_kernel<<<BB * 4, 256, 0, stream>>>(Sc0, Sh0, Sc1, Sh1, exi, Wo, bo, out);
}